// Round 15
// baseline (405.185 us; speedup 1.0000x reference)
//
#include <hip/hip_runtime.h>
#include <hip/hip_bf16.h>
#include <stdint.h>

typedef __bf16 bf16_t;
typedef __bf16 bf16x4 __attribute__((ext_vector_type(4)));
typedef __bf16 bf16x8 __attribute__((ext_vector_type(8)));
typedef float  f32x4  __attribute__((ext_vector_type(4)));
typedef long long i64;
typedef long long i64x2 __attribute__((ext_vector_type(2)));

#define MFMA16(a, b, c) __builtin_amdgcn_mfma_f32_16x16x32_bf16((a), (b), (c), 0, 0, 0)
#define MFMAF8(a, b, c) __builtin_amdgcn_mfma_f32_16x16x32_fp8_fp8((a), (b), (c), 0, 0, 0)

static constexpr int TOKS   = 16384;  // B*N
static constexpr int SEQ    = 4096;
static constexpr int DIMK   = 1024;
static constexpr int H2     = 4096;   // 2*HIDDEN
static constexpr int HID    = 2048;
static constexpr int QKD    = 128;
static constexpr int SMEM8P = 131072; // fp8: 2buf x 2half x 128rows x 128B x (A,B)
// P storage (fp8): per (batch, rb) panel [256][(rb+1)*256] bytes
static constexpr size_t PBATCH = 8912896;  // 65536 * 136 bytes per batch

__device__ __forceinline__ void gload_lds16b(const uint8_t* g, uint8_t* l) {
  __builtin_amdgcn_global_load_lds((__attribute__((address_space(1))) void*)(g),
                                   (__attribute__((address_space(3))) void*)(l),
                                   16, 0, 0);
}

__device__ __forceinline__ float silu_f(float v) { return v / (1.0f + __expf(-v)); }

__device__ __forceinline__ uint32_t f8x4(float a, float b, float c, float d) {
  int v = __builtin_amdgcn_cvt_pk_fp8_f32(a, b, 0, false);
  v = __builtin_amdgcn_cvt_pk_fp8_f32(c, d, v, true);
  return (uint32_t)v;
}
__device__ __forceinline__ uint8_t f8x1(float a) {
  return (uint8_t)(__builtin_amdgcn_cvt_pk_fp8_f32(a, 0.f, 0, false) & 0xff);
}

// k-permutation within a 128-byte k-tile: [a|s|t|b] -> [a|t|s|b].
// Makes the fragment granule pair (8a+t, 8a+4+t) 16B-contiguous so the core
// reads ds_read_b128. A.B is invariant: SAME perm applied to A and B k-dims.
__device__ __forceinline__ int permk(int kb) {
  int b = kb & 7, t = (kb >> 3) & 3, s = (kb >> 5) & 1, a = (kb >> 6) & 1;
  return (a << 6) | (t << 4) | (s << 3) | b;
}

#define BARRIER() __builtin_amdgcn_s_barrier()

// ---------------------------------------------------------------------------
// Weight transpose: W[K][N] f32 -> WT[N][K] bf16 (for Wqk)
// ---------------------------------------------------------------------------
__global__ __launch_bounds__(256) void k_transpose_bf16(const float* __restrict__ W,
                                                        bf16_t* __restrict__ WT,
                                                        int K, int N) {
  __shared__ float t[32][33];
  int n0 = blockIdx.x * 32, k0 = blockIdx.y * 32;
  int tx = threadIdx.x & 31, ty = threadIdx.x >> 5;
#pragma unroll
  for (int r = 0; r < 32; r += 8)
    t[ty + r][tx] = W[(size_t)(k0 + ty + r) * N + n0 + tx];
  __syncthreads();
#pragma unroll
  for (int r = 0; r < 32; r += 8)
    WT[(size_t)(n0 + ty + r) * K + k0 + tx] = (bf16_t)t[tx][ty + r];
}

// Weight transpose: W[K][N] f32 -> WT[N][K] fp8 (k-permuted), scaled x16
__global__ __launch_bounds__(256) void k_transpose_f8(const float* __restrict__ W,
                                                      uint8_t* __restrict__ WT,
                                                      int K, int N) {
  __shared__ float t[32][33];
  int n0 = blockIdx.x * 32, k0 = blockIdx.y * 32;
  int tx = threadIdx.x & 31, ty = threadIdx.x >> 5;
#pragma unroll
  for (int r = 0; r < 32; r += 8)
    t[ty + r][tx] = W[(size_t)(k0 + ty + r) * N + n0 + tx];
  __syncthreads();
#pragma unroll
  for (int r = 0; r < 32; r += 8) {
    int kt = k0 + tx;
    WT[(size_t)(n0 + ty + r) * K + (kt & ~127) + permk(kt & 127)] =
        f8x1(t[tx][ty + r] * 16.0f);
  }
}

// ---------------------------------------------------------------------------
// LayerNorm: x f32 -> normed bf16 (qk GEMM) + normed fp8 k-permuted (hidden)
// ---------------------------------------------------------------------------
__global__ __launch_bounds__(256) void k_layernorm(const float* __restrict__ x,
                                                   const float* __restrict__ g,
                                                   const float* __restrict__ b,
                                                   bf16_t* __restrict__ out,
                                                   uint8_t* __restrict__ out8) {
  int row = blockIdx.x, t = threadIdx.x;
  const float4* xr = (const float4*)(x + (size_t)row * DIMK);
  float4 v = xr[t];
  float s  = v.x + v.y + v.z + v.w;
  float ss = v.x * v.x + v.y * v.y + v.z * v.z + v.w * v.w;
#pragma unroll
  for (int o = 1; o < 64; o <<= 1) { s += __shfl_xor(s, o); ss += __shfl_xor(ss, o); }
  __shared__ float red[8];
  int wave = t >> 6, lane = t & 63;
  if (lane == 0) { red[wave] = s; red[wave + 4] = ss; }
  __syncthreads();
  s  = red[0] + red[1] + red[2] + red[3];
  ss = red[4] + red[5] + red[6] + red[7];
  float mean = s * (1.0f / DIMK);
  float var  = ss * (1.0f / DIMK) - mean * mean;
  float rstd = rsqrtf(var + 1e-5f);
  float4 gg = ((const float4*)g)[t];
  float4 bb = ((const float4*)b)[t];
  float o0 = (v.x - mean) * rstd * gg.x + bb.x;
  float o1 = (v.y - mean) * rstd * gg.y + bb.y;
  float o2 = (v.z - mean) * rstd * gg.z + bb.z;
  float o3 = (v.w - mean) * rstd * gg.w + bb.w;
  bf16x4 o4; o4[0] = (bf16_t)o0; o4[1] = (bf16_t)o1; o4[2] = (bf16_t)o2; o4[3] = (bf16_t)o3;
  *(bf16x4*)(out + (size_t)row * DIMK + t * 4) = o4;
  int kt = t * 4;
  *(uint32_t*)(out8 + (size_t)row * DIMK + (kt & ~127) + permk(kt & 127)) =
      f8x4(o0, o1, o2, o3);
}

// ---------------------------------------------------------------------------
// fp8 2-PHASE 256x256 GEMM core, BK=128. 512 thr / 8 waves (2M x 4N).
// TWO barriers per K-tile (was 4): phase0 = all-mi x kp0 (64 MFMA/wave),
// phase1 = kp1. Reads lead their MFMA by one phase (p0 reads kp1; p1 reads
// kp0(g+1) after the drain). Staging: A(g+1) at p0, B(g+2) at p1; single
// counted vmcnt(4) per K-tile (outstanding at g.p1 = B(g+2)4 + A(g+1)4 ->
// keep 4 = B(g+2); drains tile g+1). K-permuted operands (permk) keep all
// fragment reads as conflict-free ds_read_b128 (measured 0 in r14).
// ---------------------------------------------------------------------------
#define MFMAQ8(MH, KP)                                                        \
  _Pragma("unroll")                                                           \
  for (int mi = 0; mi < 4; ++mi)                                              \
    _Pragma("unroll")                                                         \
    for (int nj = 0; nj < 4; ++nj)                                            \
      _Pragma("unroll")                                                       \
      for (int ks = 0; ks < 2; ++ks)                                          \
        acc[(MH) * 4 + mi][nj] = MFMAF8(aF[(MH) * 4 + mi][KP][ks],            \
                                        bF[nj][KP][ks], acc[(MH) * 4 + mi][nj]);

#define RDA8(MILO, KP, BUFO)                                                  \
  _Pragma("unroll")                                                           \
  for (int mi = (MILO); mi < (MILO) + 4; ++mi)                                \
    aF[mi][KP] = *(const i64x2*)(pA + (BUFO) + mi * 2048 + swc[KP]);

#define RDB8(KP, BUFO)                                                        \
  _Pragma("unroll")                                                           \
  for (int nj = 0; nj < 4; ++nj)                                              \
    bF[nj][KP] = *(const i64x2*)(pB + (BUFO) + nj * 2048 + swc[KP]);

__device__ __forceinline__ void core8p_f8(const uint8_t* __restrict__ Ag, int lda,
                                          const uint8_t* __restrict__ Bg, int ldb,
                                          int NK, uint8_t* AS, uint8_t* BS,
                                          f32x4 (&acc)[8][4]) {
  const int tid = threadIdx.x, wid = tid >> 6, lane = tid & 63;
  const int wm = wid >> 2, wn = wid & 3;
  const int srow = lane >> 3;                       // row within 8-row chunk
  const int scol = ((lane & 7) ^ srow) * 16;        // pre-swizzled source chunk

  auto stA = [&](int kt, int h) {
    int r0 = h * 128 + wid * 16 + srow;
    uint8_t* d = AS + ((kt & 1) * 2 + h) * 16384 + wid * 2048;
    gload_lds16b(Ag + (size_t)r0 * lda + kt * 128 + scol, d);
    gload_lds16b(Ag + (size_t)(r0 + 8) * lda + kt * 128 + scol, d + 1024);
  };
  auto stB = [&](int kt, int h) {
    int r0 = h * 128 + wid * 16 + srow;
    uint8_t* d = BS + ((kt & 1) * 2 + h) * 16384 + wid * 2048;
    gload_lds16b(Bg + (size_t)r0 * ldb + kt * 128 + scol, d);
    gload_lds16b(Bg + (size_t)(r0 + 8) * ldb + kt * 128 + scol, d + 1024);
  };

  const int t = lane >> 4;
  int swc[2];
  swc[0] = ((0 * 4 + t) ^ (lane & 7)) * 16;
  swc[1] = ((1 * 4 + t) ^ (lane & 7)) * 16;

  const uint8_t* pA = AS + wm * 16384 + (lane & 15) * 128;
  const uint8_t* pB = BS + (wn >> 1) * 16384 + ((wn & 1) * 64 + (lane & 15)) * 128;

  i64x2 aF[8][2], bF[4][2];

  // Prologue: stage A(0),B(0),B(1); vmcnt(4) drains tile 0 (keeps B(1));
  // read all kp0 frags of tile 0.
  stA(0, 0); stA(0, 1); stB(0, 0); stB(0, 1);
  stB(1, 0); stB(1, 1);
  asm volatile("s_waitcnt vmcnt(4)" ::: "memory");
  BARRIER();
  RDA8(0, 0, 0);
  RDA8(4, 0, 0);
  RDB8(0, 0);

  for (int g = 0; g < NK; ++g) {
    const int buf  = (g & 1) * 32768;
    const int nbuf = ((g + 1) & 1) * 32768;
    // ---- p0: read kp1 frags (12 b128); stage A(g+1); BAR; MFMA kp0 (64)
    RDA8(0, 1, buf);
    RDA8(4, 1, buf);
    RDB8(1, buf);
    if (g + 1 < NK) { stA(g + 1, 0); stA(g + 1, 1); }
    BARRIER();
    __builtin_amdgcn_s_setprio(1);
    MFMAQ8(0, 0);
    MFMAQ8(1, 0);
    __builtin_amdgcn_s_setprio(0);
    // ---- p1: stage B(g+2); drain tile g+1 (keep B(g+2)); BAR;
    //          read kp0(g+1); MFMA kp1 (64)
    if (g + 2 < NK) {
      stB(g + 2, 0); stB(g + 2, 1);
      asm volatile("s_waitcnt vmcnt(4)" ::: "memory");
    } else if (g + 1 < NK) {
      asm volatile("s_waitcnt vmcnt(0)" ::: "memory");
    }
    BARRIER();
    if (g + 1 < NK) {
      RDA8(0, 0, nbuf);
      RDA8(4, 0, nbuf);
      RDB8(0, nbuf);
    }
    __builtin_amdgcn_s_setprio(1);
    MFMAQ8(0, 1);
    MFMAQ8(1, 1);
    __builtin_amdgcn_s_setprio(0);
  }
}

// GEMM1: silu(normed @ Wh + bh) -> vT8 (fp8 x16, transposed, tok-permuted) /
// gate bf16.  A = normed8 (s=1), B = Wh8T (s=16): pre-act = acc/16 + bias.
__global__ __launch_bounds__(512, 2) void k_gemm_hidden8p(const uint8_t* __restrict__ A,
                                                          const uint8_t* __restrict__ BT,
                                                          const float* __restrict__ bias,
                                                          uint8_t* __restrict__ vT8,
                                                          bf16_t* __restrict__ gate) {
  extern __shared__ __align__(16) uint8_t lds[];
  uint8_t* AS = lds;
  uint8_t* BS = lds + 65536;
  const int nwg = gridDim.x, bid = blockIdx.x;
  const int swz = (bid & 7) * (nwg >> 3) + (bid >> 3);
  const int mblk = swz >> 4, nblk = swz & 15;            // H2/256 = 16
  const int m0 = mblk * 256, n0 = nblk * 256;
  f32x4 acc[8][4];
#pragma unroll
  for (int i = 0; i < 8; ++i)
#pragma unroll
    for (int j = 0; j < 4; ++j) acc[i][j] = (f32x4){0.f, 0.f, 0.f, 0.f};
  core8p_f8(A + (size_t)m0 * DIMK, DIMK, BT + (size_t)n0 * DIMK, DIMK,
            DIMK / 128, AS, BS, acc);

  const int tid = threadIdx.x, wid = tid >> 6, lane = tid & 63;
  const int wm = wid >> 2, wn = wid & 3;
  const int row0 = m0 + wm * 128, col0 = n0 + wn * 64;
#pragma unroll
  for (int mi = 0; mi < 8; ++mi)
#pragma unroll
    for (int nj = 0; nj < 4; ++nj) {
      int col = col0 + nj * 16 + (lane & 15);
      float bv = bias[col];
      int row = row0 + mi * 16 + ((lane >> 4) << 2);
      float sv[4];
#pragma unroll
      for (int r = 0; r < 4; ++r) sv[r] = silu_f(acc[mi][nj][r] * 0.0625f + bv);
      if (col < HID) {
        *(uint32_t*)(vT8 + (size_t)col * TOKS + (row & ~127) + permk(row & 127)) =
            f8x4(sv[0] * 16.f, sv[1] * 16.f, sv[2] * 16.f, sv[3] * 16.f);
      } else {
#pragma unroll
        for (int r = 0; r < 4; ++r)
          gate[(size_t)(row + r) * HID + (col - HID)] = (bf16_t)sv[r];
      }
    }
}

// Final GEMM: out = gated @ Wo + bo + x. A = gated8 (x256), B = Wo8T (x16).
__global__ __launch_bounds__(512, 2) void k_gemm_out8p(const uint8_t* __restrict__ A,
                                                       const uint8_t* __restrict__ BT,
                                                       const float* __restrict__ bo,
                                                       const float* __restrict__ x,
                                                       float* __restrict__ out) {
  extern __shared__ __align__(16) uint8_t lds[];
  uint8_t* AS = lds;
  uint8_t* BS = lds + 65536;
  const int nwg = gridDim.x, bid = blockIdx.x;
  const int swz = (bid & 7) * (nwg >> 3) + (bid >> 3);
  const int mblk = swz >> 2, nblk = swz & 3;             // DIMK/256 = 4
  const int m0 = mblk * 256, n0 = nblk * 256;
  f32x4 acc[8][4];
#pragma unroll
  for (int i = 0; i < 8; ++i)
#pragma unroll
    for (int j = 0; j < 4; ++j) acc[i][j] = (f32x4){0.f, 0.f, 0.f, 0.f};
  core8p_f8(A + (size_t)m0 * HID, HID, BT + (size_t)n0 * HID, HID,
            HID / 128, AS, BS, acc);

  const int tid = threadIdx.x, wid = tid >> 6, lane = tid & 63;
  const int wm = wid >> 2, wn = wid & 3;
  const int row0 = m0 + wm * 128, col0 = n0 + wn * 64;
#pragma unroll
  for (int mi = 0; mi < 8; ++mi)
#pragma unroll
    for (int nj = 0; nj < 4; ++nj) {
      int col = col0 + nj * 16 + (lane & 15);
      float bv = bo[col];
      int row = row0 + mi * 16 + ((lane >> 4) << 2);
#pragma unroll
      for (int r = 0; r < 4; ++r) {
        size_t gi = (size_t)(row + r) * DIMK + col;
        out[gi] = acc[mi][nj][r] * (1.0f / 4096.0f) + bv + x[gi];
      }
    }
}

// PV: A = P8 (x2^18, j-permuted panels), B = vT8 (x16, tok-permuted);
// heavy-first grid. gated8 = fp8(acc * gate * 2^-14), k(HID)-permuted.
__global__ __launch_bounds__(512, 2) void k_pv8p(const uint8_t* __restrict__ P8,
                                                 const uint8_t* __restrict__ vT8,
                                                 const bf16_t* __restrict__ gate,
                                                 uint8_t* __restrict__ gated8) {
  extern __shared__ __align__(16) uint8_t lds[];
  uint8_t* AS = lds;
  uint8_t* BS = lds + 65536;
  const int w = blockIdx.x;
  const int rb = 15 - (w >> 5);
  const int hb = (w >> 2) & 7;
  const int bb = w & 3;
  const int lda = (rb + 1) * 256;
  const uint8_t* Ag = P8 + (size_t)bb * PBATCH + (size_t)65536 * (rb * (rb + 1) / 2);
  const uint8_t* Bg = vT8 + (size_t)(hb * 256) * TOKS + (size_t)bb * SEQ;
  f32x4 acc[8][4];
#pragma unroll
  for (int i = 0; i < 8; ++i)
#pragma unroll
    for (int j = 0; j < 4; ++j) acc[i][j] = (f32x4){0.f, 0.f, 0.f, 0.f};
  core8p_f8(Ag, lda, Bg, TOKS, (rb + 1) * 2, AS, BS, acc);

  const int tid = threadIdx.x, wid = tid >> 6, lane = tid & 63;
  const int wm = wid >> 2, wn = wid & 3;
  const int row0 = rb * 256 + wm * 128, col0 = hb * 256 + wn * 64;
#pragma unroll
  for (int mi = 0; mi < 8; ++mi)
#pragma unroll
    for (int nj = 0; nj < 4; ++nj) {
      int col = col0 + nj * 16 + (lane & 15);
      int pcol = (col & ~127) | permk(col & 127);
#pragma unroll
      for (int r = 0; r < 4; ++r) {
        int row = row0 + mi * 16 + ((lane >> 4) << 2) + r;
        size_t tok = (size_t)(bb * SEQ + row);
        float gv = (float)gate[tok * HID + col];
        gated8[tok * HID + pcol] = f8x1(acc[mi][nj][r] * gv * 6.103515625e-05f);
      }
    }
}

// ---------------------------------------------------------------------------
// 128x128 m97-style bf16 core (kept for qk / qkt)
// ---------------------------------------------------------------------------
__device__ __forceinline__ void gload_lds16(const bf16_t* g, bf16_t* l) {
  __builtin_amdgcn_global_load_lds((__attribute__((address_space(1))) void*)(g),
                                   (__attribute__((address_space(3))) void*)(l),
                                   16, 0, 0);
}

__device__ __forceinline__ void gemm_core_std(const bf16_t* __restrict__ Ag0, int lda,
                                              const bf16_t* __restrict__ Bg0, int ldb,
                                              int K, bf16_t* As, bf16_t* Bs,
                                              f32x4 acc[4][4]) {
  const int tid = threadIdx.x;
  const int wave = tid >> 6, lane = tid & 63;
  bf16_t* asw = As + wave * 32 * 32;
  bf16_t* bsw = Bs + wave * 32 * 32;
  const int ar = ((wave >> 1) * 64 + (lane & 15)) * 32 + (lane >> 4) * 8;
  const int br = ((wave & 1) * 64 + (lane & 15)) * 32 + (lane >> 4) * 8;
  for (int k0 = 0; k0 < K; k0 += 32) {
    __syncthreads();
    gload_lds16(Ag0 + k0, asw);
    gload_lds16(Ag0 + k0 + 16 * lda, asw + 16 * 32);
    gload_lds16(Bg0 + k0, bsw);
    gload_lds16(Bg0 + k0 + 16 * ldb, bsw + 16 * 32);
    __syncthreads();
    bf16x8 af[4], bfr[4];
#pragma unroll
    for (int m = 0; m < 4; m++) af[m] = *(const bf16x8*)(As + ar + m * 16 * 32);
#pragma unroll
    for (int n = 0; n < 4; n++) bfr[n] = *(const bf16x8*)(Bs + br + n * 16 * 32);
#pragma unroll
    for (int m = 0; m < 4; m++)
#pragma unroll
      for (int n = 0; n < 4; n++) acc[m][n] = MFMA16(af[m], bfr[n], acc[m][n]);
  }
}

// qk GEMM (bf16): qkv = silu(normed @ Wqk + bqk); q/k = qkv*gamma+beta
__global__ __launch_bounds__(256) void k_gemm_qk(const bf16_t* __restrict__ A,
                                                 const bf16_t* __restrict__ BT,
                                                 const float* __restrict__ bias,
                                                 const float* __restrict__ osg,
                                                 const float* __restrict__ osb,
                                                 bf16_t* __restrict__ qo,
                                                 bf16_t* __restrict__ ko) {
  __shared__ __align__(16) bf16_t As[128 * 32];
  __shared__ __align__(16) bf16_t Bs[128 * 32];
  const int tid = threadIdx.x, wave = tid >> 6, lane = tid & 63;
  const int m0 = blockIdx.y * 128;
  const bf16_t* Ag0 = A + (size_t)(m0 + wave * 32 + (lane >> 2)) * DIMK + (lane & 3) * 8;
  const bf16_t* Bg0 = BT + (size_t)(wave * 32 + (lane >> 2)) * DIMK + (lane & 3) * 8;
  f32x4 acc[4][4];
#pragma unroll
  for (int m = 0; m < 4; m++)
#pragma unroll
    for (int n = 0; n < 4; n++) acc[m][n] = (f32x4){0.f, 0.f, 0.f, 0.f};
  gemm_core_std(Ag0, DIMK, Bg0, DIMK, DIMK, As, Bs, acc);

  const int row0 = m0 + (wave >> 1) * 64;
  const int col0 = (wave & 1) * 64;
#pragma unroll
  for (int m = 0; m < 4; m++) {
#pragma unroll
    for (int n = 0; n < 4; n++) {
      int col = col0 + n * 16 + (lane & 15);
      float bv = bias[col];
      float g0 = osg[col], b0 = osb[col];
      float g1 = osg[QKD + col], b1 = osb[QKD + col];
      int row = row0 + m * 16 + ((lane >> 4) << 2);
#pragma unroll
      for (int r = 0; r < 4; r++) {
        float sv = silu_f(acc[m][n][r] + bv);
        qo[(size_t)(row + r) * QKD + col] = (bf16_t)(sv * g0 + b0);
        ko[(size_t)(row + r) * QKD + col] = (bf16_t)(sv * g1 + b1);
      }
    }
  }
}

// Pass A (bf16 core): P = relu((q@k^T)/(i+1))^2, causal, written fp8 x2^18
// j-PERMUTED into rect per-(bb,rb) panels. Even-ib jb=ib+1 tile = zeros
// (permutation-invariant: whole tile zeroed).
__global__ __launch_bounds__(256) void k_qkt(const bf16_t* __restrict__ qb,
                                             const bf16_t* __restrict__ kb,
                                             uint8_t* __restrict__ P8) {
  const int jb = blockIdx.x, ib = blockIdx.y, bb = blockIdx.z;
  const int rb = ib >> 1;
  if (jb > 2 * rb + 1) return;
  const int lda = (rb + 1) * 256;
  uint8_t* Pt = P8 + (size_t)bb * PBATCH + (size_t)65536 * (rb * (rb + 1) / 2)
              + (size_t)((ib & 1) * 128) * lda + jb * 128;
  if (jb == ib + 1) {  // fully masked tile -> zeros
    const int row = threadIdx.x >> 1, cb = (threadIdx.x & 1) * 64;
    uint4 z = {0, 0, 0, 0};
#pragma unroll
    for (int c = 0; c < 64; c += 16)
      *(uint4*)(Pt + (size_t)row * lda + cb + c) = z;
    return;
  }
  __shared__ __align__(16) bf16_t As[128 * 32];
  __shared__ __align__(16) bf16_t Bs[128 * 32];
  const int tid = threadIdx.x, wave = tid >> 6, lane = tid & 63;
  const bf16_t* Ag0 = qb + (size_t)(bb * SEQ + ib * 128 + wave * 32 + (lane >> 2)) * QKD + (lane & 3) * 8;
  const bf16_t* Bg0 = kb + (size_t)(bb * SEQ + jb * 128 + wave * 32 + (lane >> 2)) * QKD + (lane & 3) * 8;
  f32x4 acc[4][4];
#pragma unroll
  for (int m = 0; m < 4; m++)
#pragma unroll
    for (int n = 0; n < 4; n++) acc[m][n] = (f32x4){0.f, 0.f, 0.f, 0.f};
  gemm_core_std(Ag0, QKD, Bg0, QKD, QKD, As, Bs, acc);

  const int il0 = (wave >> 1) * 64, jl0 = (wave & 1) * 64;
#pragma unroll
  for (int m = 0; m < 4; m++) {
#pragma unroll
    for (int n = 0; n < 4; n++) {
      int jloc = jl0 + n * 16 + (lane & 15);
      int jg = jb * 128 + jloc;
      int jp = permk(jloc);
#pragma unroll
      for (int r = 0; r < 4; r++) {
        int iloc = il0 + m * 16 + ((lane >> 4) << 2) + r;
        int ig = ib * 128 + iloc;
        float sv = acc[m][n][r] / (float)(ig + 1);
        sv = fmaxf(sv, 0.f);
        sv *= sv;
        if (jg > ig) sv = 0.f;
        Pt[(size_t)iloc * lda + jp] = f8x1(sv * 262144.0f);  // x2^18
      }
    }
  }
}

// ---------------------------------------------------------------------------
extern "C" void kernel_launch(void* const* d_in, const int* in_sizes, int n_in,
                              void* d_out, int out_size, void* d_ws, size_t ws_size,
                              hipStream_t stream) {
  (void)in_sizes; (void)n_in; (void)out_size; (void)ws_size;
  const float* x    = (const float*)d_in[0];
  const float* ln_g = (const float*)d_in[1];
  const float* ln_b = (const float*)d_in[2];
  const float* Wh   = (const float*)d_in[3];
  const float* bh   = (const float*)d_in[4];
  const float* Wqk  = (const float*)d_in[5];
  const float* bqk  = (const float*)d_in[6];
  const float* osg  = (const float*)d_in[7];
  const float* osb  = (const float*)d_in[8];
  const float* Wo   = (const float*)d_in[9];
  const float* bo   = (const float*)d_in[10];
  float* out = (float*)d_out;

  char* ws = (char*)d_ws;
  bf16_t* normed  = (bf16_t*)ws;  ws += (size_t)TOKS * DIMK * 2;   // 32 MB
  uint8_t* normed8 = (uint8_t*)ws; ws += (size_t)TOKS * DIMK;      // 16 MB
  bf16_t* WqkT    = (bf16_t*)ws;  ws += (size_t)QKD * DIMK * 2;    // 0.25 MB
  uint8_t* Wh8T   = (uint8_t*)ws; ws += (size_t)H2 * DIMK;         // 4 MB
  uint8_t* Wo8T   = (uint8_t*)ws; ws += (size_t)DIMK * HID;        // 2 MB
  bf16_t* gate    = (bf16_t*)ws;  ws += (size_t)TOKS * HID * 2;    // 64 MB
  uint8_t* vT8    = (uint8_t*)ws; ws += (size_t)HID * TOKS;        // 32 MB
  uint8_t* gated8 = (uint8_t*)ws; ws += (size_t)TOKS * HID;        // 32 MB
  bf16_t* qb      = (bf16_t*)ws;  ws += (size_t)TOKS * QKD * 2;    // 4 MB
  bf16_t* kb      = (bf16_t*)ws;  ws += (size_t)TOKS * QKD * 2;    // 4 MB
  uint8_t* P8     = (uint8_t*)ws; ws += (size_t)4 * PBATCH;        // 35.7 MB

  hipFuncSetAttribute((const void*)k_gemm_hidden8p,
                      hipFuncAttributeMaxDynamicSharedMemorySize, SMEM8P);
  hipFuncSetAttribute((const void*)k_gemm_out8p,
                      hipFuncAttributeMaxDynamicSharedMemorySize, SMEM8P);
  hipFuncSetAttribute((const void*)k_pv8p,
                      hipFuncAttributeMaxDynamicSharedMemorySize, SMEM8P);

  k_transpose_f8<<<dim3(H2 / 32, DIMK / 32), 256, 0, stream>>>(Wh, Wh8T, DIMK, H2);
  k_transpose_f8<<<dim3(DIMK / 32, HID / 32), 256, 0, stream>>>(Wo, Wo8T, HID, DIMK);
  k_transpose_bf16<<<dim3(QKD / 32, DIMK / 32), 256, 0, stream>>>(Wqk, WqkT, DIMK, QKD);
  k_layernorm<<<TOKS, 256, 0, stream>>>(x, ln_g, ln_b, normed, normed8);
  k_gemm_hidden8p<<<dim3((TOKS / 256) * (H2 / 256)), 512, SMEM8P, stream>>>(normed8, Wh8T, bh, vT8, gate);
  k_gemm_qk<<<dim3(1, TOKS / 128), 256, 0, stream>>>(normed, WqkT, bqk, osg, osb, qb, kb);
  k_qkt<<<dim3(SEQ / 128, SEQ / 128, 4), 256, 0, stream>>>(qb, kb, P8);
  k_pv8p<<<dim3(16 * 8 * 4), 512, SMEM8P, stream>>>(P8, vT8, gate, gated8);
  k_gemm_out8p<<<dim3((TOKS / 256) * (DIMK / 256)), 512, SMEM8P, stream>>>(gated8, Wo8T, bo, x, out);
}

// Round 16
// 396.335 us; speedup vs baseline: 1.0223x; 1.0223x over previous
//
#include <hip/hip_runtime.h>
#include <hip/hip_bf16.h>
#include <stdint.h>

typedef __bf16 bf16_t;
typedef __bf16 bf16x4 __attribute__((ext_vector_type(4)));
typedef __bf16 bf16x8 __attribute__((ext_vector_type(8)));
typedef float  f32x4  __attribute__((ext_vector_type(4)));
typedef long long i64;
typedef long long i64x2 __attribute__((ext_vector_type(2)));

#define MFMA16(a, b, c) __builtin_amdgcn_mfma_f32_16x16x32_bf16((a), (b), (c), 0, 0, 0)
#define MFMAF8(a, b, c) __builtin_amdgcn_mfma_f32_16x16x32_fp8_fp8((a), (b), (c), 0, 0, 0)

static constexpr int TOKS   = 16384;  // B*N
static constexpr int SEQ    = 4096;
static constexpr int DIMK   = 1024;
static constexpr int H2     = 4096;   // 2*HIDDEN
static constexpr int HID    = 2048;
static constexpr int QKD    = 128;
static constexpr int SMEM8P = 65536;  // fp8 BK=64: 2buf x 2half x 128rows x 64B x (A,B)
// P storage (fp8): per (batch, rb) panel [256][(rb+1)*256] bytes
static constexpr size_t PBATCH = 8912896;  // 65536 * 136 bytes per batch

__device__ __forceinline__ void gload_lds16b(const uint8_t* g, uint8_t* l) {
  __builtin_amdgcn_global_load_lds((__attribute__((address_space(1))) void*)(g),
                                   (__attribute__((address_space(3))) void*)(l),
                                   16, 0, 0);
}

__device__ __forceinline__ float silu_f(float v) { return v / (1.0f + __expf(-v)); }

__device__ __forceinline__ uint32_t f8x4(float a, float b, float c, float d) {
  int v = __builtin_amdgcn_cvt_pk_fp8_f32(a, b, 0, false);
  v = __builtin_amdgcn_cvt_pk_fp8_f32(c, d, v, true);
  return (uint32_t)v;
}
__device__ __forceinline__ uint8_t f8x1(float a) {
  return (uint8_t)(__builtin_amdgcn_cvt_pk_fp8_f32(a, 0.f, 0, false) & 0xff);
}

// k-permutation within a 64-byte k-tile: [s|t|b] -> [t|s|b]  (b=3 bits,
// t=2 bits, s=1 bit). Makes each (t) fragment's (ks0,ks1) 8B pair one 16B
// chunk so the core reads ds_read_b128. A.B invariant: same perm on A and B.
__device__ __forceinline__ int permk64(int kb) {
  int b = kb & 7, t = (kb >> 3) & 3, s = (kb >> 5) & 1;
  return (t << 4) | (s << 3) | b;
}

#define BARRIER() __builtin_amdgcn_s_barrier()

// ---------------------------------------------------------------------------
// Weight transpose: W[K][N] f32 -> WT[N][K] bf16 (for Wqk)
// ---------------------------------------------------------------------------
__global__ __launch_bounds__(256) void k_transpose_bf16(const float* __restrict__ W,
                                                        bf16_t* __restrict__ WT,
                                                        int K, int N) {
  __shared__ float t[32][33];
  int n0 = blockIdx.x * 32, k0 = blockIdx.y * 32;
  int tx = threadIdx.x & 31, ty = threadIdx.x >> 5;
#pragma unroll
  for (int r = 0; r < 32; r += 8)
    t[ty + r][tx] = W[(size_t)(k0 + ty + r) * N + n0 + tx];
  __syncthreads();
#pragma unroll
  for (int r = 0; r < 32; r += 8)
    WT[(size_t)(n0 + ty + r) * K + k0 + tx] = (bf16_t)t[tx][ty + r];
}

// Weight transpose: W[K][N] f32 -> WT[N][K] fp8 (k-permuted per 64), x16
__global__ __launch_bounds__(256) void k_transpose_f8(const float* __restrict__ W,
                                                      uint8_t* __restrict__ WT,
                                                      int K, int N) {
  __shared__ float t[32][33];
  int n0 = blockIdx.x * 32, k0 = blockIdx.y * 32;
  int tx = threadIdx.x & 31, ty = threadIdx.x >> 5;
#pragma unroll
  for (int r = 0; r < 32; r += 8)
    t[ty + r][tx] = W[(size_t)(k0 + ty + r) * N + n0 + tx];
  __syncthreads();
#pragma unroll
  for (int r = 0; r < 32; r += 8) {
    int kt = k0 + tx;
    WT[(size_t)(n0 + ty + r) * K + (kt & ~63) + permk64(kt & 63)] =
        f8x1(t[tx][ty + r] * 16.0f);
  }
}

// ---------------------------------------------------------------------------
// LayerNorm: x f32 -> normed bf16 (qk GEMM) + normed fp8 k-permuted (hidden)
// ---------------------------------------------------------------------------
__global__ __launch_bounds__(256) void k_layernorm(const float* __restrict__ x,
                                                   const float* __restrict__ g,
                                                   const float* __restrict__ b,
                                                   bf16_t* __restrict__ out,
                                                   uint8_t* __restrict__ out8) {
  int row = blockIdx.x, t = threadIdx.x;
  const float4* xr = (const float4*)(x + (size_t)row * DIMK);
  float4 v = xr[t];
  float s  = v.x + v.y + v.z + v.w;
  float ss = v.x * v.x + v.y * v.y + v.z * v.z + v.w * v.w;
#pragma unroll
  for (int o = 1; o < 64; o <<= 1) { s += __shfl_xor(s, o); ss += __shfl_xor(ss, o); }
  __shared__ float red[8];
  int wave = t >> 6, lane = t & 63;
  if (lane == 0) { red[wave] = s; red[wave + 4] = ss; }
  __syncthreads();
  s  = red[0] + red[1] + red[2] + red[3];
  ss = red[4] + red[5] + red[6] + red[7];
  float mean = s * (1.0f / DIMK);
  float var  = ss * (1.0f / DIMK) - mean * mean;
  float rstd = rsqrtf(var + 1e-5f);
  float4 gg = ((const float4*)g)[t];
  float4 bb = ((const float4*)b)[t];
  float o0 = (v.x - mean) * rstd * gg.x + bb.x;
  float o1 = (v.y - mean) * rstd * gg.y + bb.y;
  float o2 = (v.z - mean) * rstd * gg.z + bb.z;
  float o3 = (v.w - mean) * rstd * gg.w + bb.w;
  bf16x4 o4; o4[0] = (bf16_t)o0; o4[1] = (bf16_t)o1; o4[2] = (bf16_t)o2; o4[3] = (bf16_t)o3;
  *(bf16x4*)(out + (size_t)row * DIMK + t * 4) = o4;
  int kt = t * 4;
  *(uint32_t*)(out8 + (size_t)row * DIMK + (kt & ~63) + permk64(kt & 63)) =
      f8x4(o0, o1, o2, o3);
}

// ---------------------------------------------------------------------------
// fp8 4-phase 256x256 GEMM core, BK=64 / 64KB LDS -> 2 blocks/CU (TLP).
// 512 thr / 8 waves (2M x 4N). LDS: A,B each 2buf x [256 rows][64B] = 16KB.
// Layout: half h rows h*128..+127 at buf + h*8192 + row_local*64; chunk c of
// row r holds content-chunk c ^ (r&3) (staging pre-swizzles the global
// source chunk; LDS dest linear). 16 rows x 4 chunks -> 8 lanes per 16B
// slot: exactly even -> b128 reads at the 8-cycle floor (no excess conflict).
// Per K-tile: 64 MFMA/wave in 4 quadrants (mh, ks); fragment b128 holds both
// ks. Reads: p3 loads next tile's aF[0..3]+bF (aF pre-Q3, bF post-Q3 per
// WAR), p0 loads aF[4..7]. Stage 1 gload/lane/half: A(g+1)@p0/p1,
// B(g+2)@p2/p3; single vmcnt(2) per K-tile (keeps B(g+2)). NK>=2.
// ---------------------------------------------------------------------------
#define MFMAQ8(MH, KS)                                                        \
  _Pragma("unroll")                                                           \
  for (int mi = 0; mi < 4; ++mi)                                              \
    _Pragma("unroll")                                                         \
    for (int nj = 0; nj < 4; ++nj)                                            \
      acc[(MH) * 4 + mi][nj] = MFMAF8(aF[(MH) * 4 + mi][KS],                  \
                                      bF[nj][KS], acc[(MH) * 4 + mi][nj]);

#define RDA8(MILO, BUFO)                                                      \
  _Pragma("unroll")                                                           \
  for (int mi = (MILO); mi < (MILO) + 4; ++mi)                                \
    aF[mi] = *(const i64x2*)(pA + (BUFO) + mi * 1024);

#define RDB8(BUFO)                                                            \
  _Pragma("unroll")                                                           \
  for (int nj = 0; nj < 4; ++nj)                                              \
    bF[nj] = *(const i64x2*)(pB + (BUFO) + nj * 1024);

__device__ __forceinline__ void core8p_f8(const uint8_t* __restrict__ Ag, int lda,
                                          const uint8_t* __restrict__ Bg, int ldb,
                                          int NK, uint8_t* AS, uint8_t* BS,
                                          f32x4 (&acc)[8][4]) {
  const int tid = threadIdx.x, wid = tid >> 6, lane = tid & 63;
  const int wm = wid >> 2, wn = wid & 3;
  const int srow = lane >> 2;                          // row within 16-row chunk
  const int scol = ((lane & 3) ^ (srow & 3)) * 16;     // pre-swizzled src chunk

  auto stA = [&](int kt, int h) {
    int r = h * 128 + wid * 16 + srow;
    gload_lds16b(Ag + (size_t)r * lda + kt * 64 + scol,
                 AS + (kt & 1) * 16384 + h * 8192 + wid * 1024);
  };
  auto stB = [&](int kt, int h) {
    int r = h * 128 + wid * 16 + srow;
    gload_lds16b(Bg + (size_t)r * ldb + kt * 64 + scol,
                 BS + (kt & 1) * 16384 + h * 8192 + wid * 1024);
  };

  const int swc = (((lane >> 4) ^ (lane & 3)) * 16);
  const uint8_t* pA = AS + wm * 8192 + (lane & 15) * 64 + swc;
  const uint8_t* pB = BS + (wn >> 1) * 8192 + ((wn & 1) * 64 + (lane & 15)) * 64 + swc;

  i64x2 aF[8], bF[4];

  // Prologue: stage A(0),B(0),B(1); vmcnt(2) drains tile 0 (keeps B(1));
  // read tile-0 aF[0..3] + bF.
  stA(0, 0); stA(0, 1); stB(0, 0); stB(0, 1);
  stB(1, 0); stB(1, 1);
  asm volatile("s_waitcnt vmcnt(2)" ::: "memory");
  BARRIER();
  RDA8(0, 0);
  RDB8(0);

  for (int g = 0; g < NK; ++g) {
    const int buf  = (g & 1) * 16384;
    const int nbuf = ((g + 1) & 1) * 16384;
    // p0: read aF[4..7]; stage A(g+1)h0; BAR; MFMA (mh0,ks0)
    RDA8(4, buf);
    if (g + 1 < NK) stA(g + 1, 0);
    BARRIER();
    __builtin_amdgcn_s_setprio(1);
    MFMAQ8(0, 0);
    __builtin_amdgcn_s_setprio(0);
    // p1: stage A(g+1)h1; BAR; MFMA (mh1,ks0)
    if (g + 1 < NK) stA(g + 1, 1);
    BARRIER();
    __builtin_amdgcn_s_setprio(1);
    MFMAQ8(1, 0);
    __builtin_amdgcn_s_setprio(0);
    // p2: stage B(g+2)h0; BAR; MFMA (mh0,ks1)
    if (g + 2 < NK) stB(g + 2, 0);
    BARRIER();
    __builtin_amdgcn_s_setprio(1);
    MFMAQ8(0, 1);
    __builtin_amdgcn_s_setprio(0);
    // p3: stage B(g+2)h1; drain tile g+1 (keep B(g+2)); BAR;
    //     read next aF[0..3] (safe: Q2 done); MFMA (mh1,ks1); read next bF
    if (g + 2 < NK) {
      stB(g + 2, 1);
      asm volatile("s_waitcnt vmcnt(2)" ::: "memory");
    } else if (g + 1 < NK) {
      asm volatile("s_waitcnt vmcnt(0)" ::: "memory");
    }
    BARRIER();
    if (g + 1 < NK) RDA8(0, nbuf);
    __builtin_amdgcn_s_setprio(1);
    MFMAQ8(1, 1);
    __builtin_amdgcn_s_setprio(0);
    if (g + 1 < NK) RDB8(nbuf);
  }
}

// GEMM1: silu(normed @ Wh + bh) -> vT8 (fp8 x16, transposed, tok-permuted) /
// gate bf16.  A = normed8 (s=1), B = Wh8T (s=16): pre-act = acc/16 + bias.
__global__ __launch_bounds__(512, 2) void k_gemm_hidden8p(const uint8_t* __restrict__ A,
                                                          const uint8_t* __restrict__ BT,
                                                          const float* __restrict__ bias,
                                                          uint8_t* __restrict__ vT8,
                                                          bf16_t* __restrict__ gate) {
  extern __shared__ __align__(16) uint8_t lds[];
  uint8_t* AS = lds;
  uint8_t* BS = lds + 32768;
  const int nwg = gridDim.x, bid = blockIdx.x;
  const int swz = (bid & 7) * (nwg >> 3) + (bid >> 3);
  const int mblk = swz >> 4, nblk = swz & 15;            // H2/256 = 16
  const int m0 = mblk * 256, n0 = nblk * 256;
  f32x4 acc[8][4];
#pragma unroll
  for (int i = 0; i < 8; ++i)
#pragma unroll
    for (int j = 0; j < 4; ++j) acc[i][j] = (f32x4){0.f, 0.f, 0.f, 0.f};
  core8p_f8(A + (size_t)m0 * DIMK, DIMK, BT + (size_t)n0 * DIMK, DIMK,
            DIMK / 64, AS, BS, acc);

  const int tid = threadIdx.x, wid = tid >> 6, lane = tid & 63;
  const int wm = wid >> 2, wn = wid & 3;
  const int row0 = m0 + wm * 128, col0 = n0 + wn * 64;
#pragma unroll
  for (int mi = 0; mi < 8; ++mi)
#pragma unroll
    for (int nj = 0; nj < 4; ++nj) {
      int col = col0 + nj * 16 + (lane & 15);
      float bv = bias[col];
      int row = row0 + mi * 16 + ((lane >> 4) << 2);
      float sv[4];
#pragma unroll
      for (int r = 0; r < 4; ++r) sv[r] = silu_f(acc[mi][nj][r] * 0.0625f + bv);
      if (col < HID) {
        *(uint32_t*)(vT8 + (size_t)col * TOKS + (row & ~63) + permk64(row & 63)) =
            f8x4(sv[0] * 16.f, sv[1] * 16.f, sv[2] * 16.f, sv[3] * 16.f);
      } else {
#pragma unroll
        for (int r = 0; r < 4; ++r)
          gate[(size_t)(row + r) * HID + (col - HID)] = (bf16_t)sv[r];
      }
    }
}

// Final GEMM: out = gated @ Wo + bo + x. A = gated8 (x256), B = Wo8T (x16).
__global__ __launch_bounds__(512, 2) void k_gemm_out8p(const uint8_t* __restrict__ A,
                                                       const uint8_t* __restrict__ BT,
                                                       const float* __restrict__ bo,
                                                       const float* __restrict__ x,
                                                       float* __restrict__ out) {
  extern __shared__ __align__(16) uint8_t lds[];
  uint8_t* AS = lds;
  uint8_t* BS = lds + 32768;
  const int nwg = gridDim.x, bid = blockIdx.x;
  const int swz = (bid & 7) * (nwg >> 3) + (bid >> 3);
  const int mblk = swz >> 2, nblk = swz & 3;             // DIMK/256 = 4
  const int m0 = mblk * 256, n0 = nblk * 256;
  f32x4 acc[8][4];
#pragma unroll
  for (int i = 0; i < 8; ++i)
#pragma unroll
    for (int j = 0; j < 4; ++j) acc[i][j] = (f32x4){0.f, 0.f, 0.f, 0.f};
  core8p_f8(A + (size_t)m0 * HID, HID, BT + (size_t)n0 * HID, HID,
            HID / 64, AS, BS, acc);

  const int tid = threadIdx.x, wid = tid >> 6, lane = tid & 63;
  const int wm = wid >> 2, wn = wid & 3;
  const int row0 = m0 + wm * 128, col0 = n0 + wn * 64;
#pragma unroll
  for (int mi = 0; mi < 8; ++mi)
#pragma unroll
    for (int nj = 0; nj < 4; ++nj) {
      int col = col0 + nj * 16 + (lane & 15);
      float bv = bo[col];
      int row = row0 + mi * 16 + ((lane >> 4) << 2);
#pragma unroll
      for (int r = 0; r < 4; ++r) {
        size_t gi = (size_t)(row + r) * DIMK + col;
        out[gi] = acc[mi][nj][r] * (1.0f / 4096.0f) + bv + x[gi];
      }
    }
}

// PV: A = P8 (x2^18, j-permuted panels), B = vT8 (x16, tok-permuted);
// heavy-first grid. gated8 = fp8(acc * gate * 2^-14), k(HID)-permuted.
__global__ __launch_bounds__(512, 2) void k_pv8p(const uint8_t* __restrict__ P8,
                                                 const uint8_t* __restrict__ vT8,
                                                 const bf16_t* __restrict__ gate,
                                                 uint8_t* __restrict__ gated8) {
  extern __shared__ __align__(16) uint8_t lds[];
  uint8_t* AS = lds;
  uint8_t* BS = lds + 32768;
  const int w = blockIdx.x;
  const int rb = 15 - (w >> 5);
  const int hb = (w >> 2) & 7;
  const int bb = w & 3;
  const int lda = (rb + 1) * 256;
  const uint8_t* Ag = P8 + (size_t)bb * PBATCH + (size_t)65536 * (rb * (rb + 1) / 2);
  const uint8_t* Bg = vT8 + (size_t)(hb * 256) * TOKS + (size_t)bb * SEQ;
  f32x4 acc[8][4];
#pragma unroll
  for (int i = 0; i < 8; ++i)
#pragma unroll
    for (int j = 0; j < 4; ++j) acc[i][j] = (f32x4){0.f, 0.f, 0.f, 0.f};
  core8p_f8(Ag, lda, Bg, TOKS, (rb + 1) * 4, AS, BS, acc);

  const int tid = threadIdx.x, wid = tid >> 6, lane = tid & 63;
  const int wm = wid >> 2, wn = wid & 3;
  const int row0 = rb * 256 + wm * 128, col0 = hb * 256 + wn * 64;
#pragma unroll
  for (int mi = 0; mi < 8; ++mi)
#pragma unroll
    for (int nj = 0; nj < 4; ++nj) {
      int col = col0 + nj * 16 + (lane & 15);
      int pcol = (col & ~63) | permk64(col & 63);
#pragma unroll
      for (int r = 0; r < 4; ++r) {
        int row = row0 + mi * 16 + ((lane >> 4) << 2) + r;
        size_t tok = (size_t)(bb * SEQ + row);
        float gv = (float)gate[tok * HID + col];
        gated8[tok * HID + pcol] = f8x1(acc[mi][nj][r] * gv * 6.103515625e-05f);
      }
    }
}

// ---------------------------------------------------------------------------
// 128x128 m97-style bf16 core (kept for qk / qkt)
// ---------------------------------------------------------------------------
__device__ __forceinline__ void gload_lds16(const bf16_t* g, bf16_t* l) {
  __builtin_amdgcn_global_load_lds((__attribute__((address_space(1))) void*)(g),
                                   (__attribute__((address_space(3))) void*)(l),
                                   16, 0, 0);
}

__device__ __forceinline__ void gemm_core_std(const bf16_t* __restrict__ Ag0, int lda,
                                              const bf16_t* __restrict__ Bg0, int ldb,
                                              int K, bf16_t* As, bf16_t* Bs,
                                              f32x4 acc[4][4]) {
  const int tid = threadIdx.x;
  const int wave = tid >> 6, lane = tid & 63;
  bf16_t* asw = As + wave * 32 * 32;
  bf16_t* bsw = Bs + wave * 32 * 32;
  const int ar = ((wave >> 1) * 64 + (lane & 15)) * 32 + (lane >> 4) * 8;
  const int br = ((wave & 1) * 64 + (lane & 15)) * 32 + (lane >> 4) * 8;
  for (int k0 = 0; k0 < K; k0 += 32) {
    __syncthreads();
    gload_lds16(Ag0 + k0, asw);
    gload_lds16(Ag0 + k0 + 16 * lda, asw + 16 * 32);
    gload_lds16(Bg0 + k0, bsw);
    gload_lds16(Bg0 + k0 + 16 * ldb, bsw + 16 * 32);
    __syncthreads();
    bf16x8 af[4], bfr[4];
#pragma unroll
    for (int m = 0; m < 4; m++) af[m] = *(const bf16x8*)(As + ar + m * 16 * 32);
#pragma unroll
    for (int n = 0; n < 4; n++) bfr[n] = *(const bf16x8*)(Bs + br + n * 16 * 32);
#pragma unroll
    for (int m = 0; m < 4; m++)
#pragma unroll
      for (int n = 0; n < 4; n++) acc[m][n] = MFMA16(af[m], bfr[n], acc[m][n]);
  }
}

// qk GEMM (bf16): qkv = silu(normed @ Wqk + bqk); q/k = qkv*gamma+beta
__global__ __launch_bounds__(256) void k_gemm_qk(const bf16_t* __restrict__ A,
                                                 const bf16_t* __restrict__ BT,
                                                 const float* __restrict__ bias,
                                                 const float* __restrict__ osg,
                                                 const float* __restrict__ osb,
                                                 bf16_t* __restrict__ qo,
                                                 bf16_t* __restrict__ ko) {
  __shared__ __align__(16) bf16_t As[128 * 32];
  __shared__ __align__(16) bf16_t Bs[128 * 32];
  const int tid = threadIdx.x, wave = tid >> 6, lane = tid & 63;
  const int m0 = blockIdx.y * 128;
  const bf16_t* Ag0 = A + (size_t)(m0 + wave * 32 + (lane >> 2)) * DIMK + (lane & 3) * 8;
  const bf16_t* Bg0 = BT + (size_t)(wave * 32 + (lane >> 2)) * DIMK + (lane & 3) * 8;
  f32x4 acc[4][4];
#pragma unroll
  for (int m = 0; m < 4; m++)
#pragma unroll
    for (int n = 0; n < 4; n++) acc[m][n] = (f32x4){0.f, 0.f, 0.f, 0.f};
  gemm_core_std(Ag0, DIMK, Bg0, DIMK, DIMK, As, Bs, acc);

  const int row0 = m0 + (wave >> 1) * 64;
  const int col0 = (wave & 1) * 64;
#pragma unroll
  for (int m = 0; m < 4; m++) {
#pragma unroll
    for (int n = 0; n < 4; n++) {
      int col = col0 + n * 16 + (lane & 15);
      float bv = bias[col];
      float g0 = osg[col], b0 = osb[col];
      float g1 = osg[QKD + col], b1 = osb[QKD + col];
      int row = row0 + m * 16 + ((lane >> 4) << 2);
#pragma unroll
      for (int r = 0; r < 4; r++) {
        float sv = silu_f(acc[m][n][r] + bv);
        qo[(size_t)(row + r) * QKD + col] = (bf16_t)(sv * g0 + b0);
        ko[(size_t)(row + r) * QKD + col] = (bf16_t)(sv * g1 + b1);
      }
    }
  }
}

// Pass A (bf16 core): P = relu((q@k^T)/(i+1))^2, causal, written fp8 x2^18
// j-PERMUTED (per 64) into rect per-(bb,rb) panels. Even-ib jb=ib+1 tile = 0.
__global__ __launch_bounds__(256) void k_qkt(const bf16_t* __restrict__ qb,
                                             const bf16_t* __restrict__ kb,
                                             uint8_t* __restrict__ P8) {
  const int jb = blockIdx.x, ib = blockIdx.y, bb = blockIdx.z;
  const int rb = ib >> 1;
  if (jb > 2 * rb + 1) return;
  const int lda = (rb + 1) * 256;
  uint8_t* Pt = P8 + (size_t)bb * PBATCH + (size_t)65536 * (rb * (rb + 1) / 2)
              + (size_t)((ib & 1) * 128) * lda + jb * 128;
  if (jb == ib + 1) {  // fully masked tile -> zeros
    const int row = threadIdx.x >> 1, cb = (threadIdx.x & 1) * 64;
    uint4 z = {0, 0, 0, 0};
#pragma unroll
    for (int c = 0; c < 64; c += 16)
      *(uint4*)(Pt + (size_t)row * lda + cb + c) = z;
    return;
  }
  __shared__ __align__(16) bf16_t As[128 * 32];
  __shared__ __align__(16) bf16_t Bs[128 * 32];
  const int tid = threadIdx.x, wave = tid >> 6, lane = tid & 63;
  const bf16_t* Ag0 = qb + (size_t)(bb * SEQ + ib * 128 + wave * 32 + (lane >> 2)) * QKD + (lane & 3) * 8;
  const bf16_t* Bg0 = kb + (size_t)(bb * SEQ + jb * 128 + wave * 32 + (lane >> 2)) * QKD + (lane & 3) * 8;
  f32x4 acc[4][4];
#pragma unroll
  for (int m = 0; m < 4; m++)
#pragma unroll
    for (int n = 0; n < 4; n++) acc[m][n] = (f32x4){0.f, 0.f, 0.f, 0.f};
  gemm_core_std(Ag0, QKD, Bg0, QKD, QKD, As, Bs, acc);

  const int il0 = (wave >> 1) * 64, jl0 = (wave & 1) * 64;
#pragma unroll
  for (int m = 0; m < 4; m++) {
#pragma unroll
    for (int n = 0; n < 4; n++) {
      int jloc = jl0 + n * 16 + (lane & 15);
      int jg = jb * 128 + jloc;
      int jp = (jloc & ~63) | permk64(jloc & 63);
#pragma unroll
      for (int r = 0; r < 4; r++) {
        int iloc = il0 + m * 16 + ((lane >> 4) << 2) + r;
        int ig = ib * 128 + iloc;
        float sv = acc[m][n][r] / (float)(ig + 1);
        sv = fmaxf(sv, 0.f);
        sv *= sv;
        if (jg > ig) sv = 0.f;
        Pt[(size_t)iloc * lda + jp] = f8x1(sv * 262144.0f);  // x2^18
      }
    }
  }
}

// ---------------------------------------------------------------------------
extern "C" void kernel_launch(void* const* d_in, const int* in_sizes, int n_in,
                              void* d_out, int out_size, void* d_ws, size_t ws_size,
                              hipStream_t stream) {
  (void)in_sizes; (void)n_in; (void)out_size; (void)ws_size;
  const float* x    = (const float*)d_in[0];
  const float* ln_g = (const float*)d_in[1];
  const float* ln_b = (const float*)d_in[2];
  const float* Wh   = (const float*)d_in[3];
  const float* bh   = (const float*)d_in[4];
  const float* Wqk  = (const float*)d_in[5];
  const float* bqk  = (const float*)d_in[6];
  const float* osg  = (const float*)d_in[7];
  const float* osb  = (const float*)d_in[8];
  const float* Wo   = (const float*)d_in[9];
  const float* bo   = (const float*)d_in[10];
  float* out = (float*)d_out;

  char* ws = (char*)d_ws;
  bf16_t* normed  = (bf16_t*)ws;  ws += (size_t)TOKS * DIMK * 2;   // 32 MB
  uint8_t* normed8 = (uint8_t*)ws; ws += (size_t)TOKS * DIMK;      // 16 MB
  bf16_t* WqkT    = (bf16_t*)ws;  ws += (size_t)QKD * DIMK * 2;    // 0.25 MB
  uint8_t* Wh8T   = (uint8_t*)ws; ws += (size_t)H2 * DIMK;         // 4 MB
  uint8_t* Wo8T   = (uint8_t*)ws; ws += (size_t)DIMK * HID;        // 2 MB
  bf16_t* gate    = (bf16_t*)ws;  ws += (size_t)TOKS * HID * 2;    // 64 MB
  uint8_t* vT8    = (uint8_t*)ws; ws += (size_t)HID * TOKS;        // 32 MB
  uint8_t* gated8 = (uint8_t*)ws; ws += (size_t)TOKS * HID;        // 32 MB
  bf16_t* qb      = (bf16_t*)ws;  ws += (size_t)TOKS * QKD * 2;    // 4 MB
  bf16_t* kb      = (bf16_t*)ws;  ws += (size_t)TOKS * QKD * 2;    // 4 MB
  uint8_t* P8     = (uint8_t*)ws; ws += (size_t)4 * PBATCH;        // 35.7 MB

  hipFuncSetAttribute((const void*)k_gemm_hidden8p,
                      hipFuncAttributeMaxDynamicSharedMemorySize, SMEM8P);
  hipFuncSetAttribute((const void*)k_gemm_out8p,
                      hipFuncAttributeMaxDynamicSharedMemorySize, SMEM8P);
  hipFuncSetAttribute((const void*)k_pv8p,
                      hipFuncAttributeMaxDynamicSharedMemorySize, SMEM8P);

  k_transpose_f8<<<dim3(H2 / 32, DIMK / 32), 256, 0, stream>>>(Wh, Wh8T, DIMK, H2);
  k_transpose_f8<<<dim3(DIMK / 32, HID / 32), 256, 0, stream>>>(Wo, Wo8T, HID, DIMK);
  k_transpose_bf16<<<dim3(QKD / 32, DIMK / 32), 256, 0, stream>>>(Wqk, WqkT, DIMK, QKD);
  k_layernorm<<<TOKS, 256, 0, stream>>>(x, ln_g, ln_b, normed, normed8);
  k_gemm_hidden8p<<<dim3((TOKS / 256) * (H2 / 256)), 512, SMEM8P, stream>>>(normed8, Wh8T, bh, vT8, gate);
  k_gemm_qk<<<dim3(1, TOKS / 128), 256, 0, stream>>>(normed, WqkT, bqk, osg, osb, qb, kb);
  k_qkt<<<dim3(SEQ / 128, SEQ / 128, 4), 256, 0, stream>>>(qb, kb, P8);
  k_pv8p<<<dim3(16 * 8 * 4), 512, SMEM8P, stream>>>(P8, vT8, gate, gated8);
  k_gemm_out8p<<<dim3((TOKS / 256) * (DIMK / 256)), 512, SMEM8P, stream>>>(gated8, Wo8T, bo, x, out);
}

// Round 17
// 389.973 us; speedup vs baseline: 1.0390x; 1.0163x over previous
//
#include <hip/hip_runtime.h>
#include <hip/hip_bf16.h>
#include <stdint.h>

typedef __bf16 bf16_t;
typedef __bf16 bf16x4 __attribute__((ext_vector_type(4)));
typedef __bf16 bf16x8 __attribute__((ext_vector_type(8)));
typedef float  f32x4  __attribute__((ext_vector_type(4)));
typedef long long i64;
typedef long long i64x2 __attribute__((ext_vector_type(2)));

#define MFMA16(a, b, c) __builtin_amdgcn_mfma_f32_16x16x32_bf16((a), (b), (c), 0, 0, 0)
#define MFMAF8(a, b, c) __builtin_amdgcn_mfma_f32_16x16x32_fp8_fp8((a), (b), (c), 0, 0, 0)

static constexpr int TOKS   = 16384;  // B*N
static constexpr int SEQ    = 4096;
static constexpr int DIMK   = 1024;
static constexpr int H2     = 4096;   // 2*HIDDEN
static constexpr int HID    = 2048;
static constexpr int QKD    = 128;
static constexpr int SMEM8P = 131072; // fp8: 2buf x 2half x 128rows x 128B x (A,B)
// P storage (fp8): per (batch, rb) panel [256][(rb+1)*256] bytes
static constexpr size_t PBATCH = 8912896;  // 65536 * 136 bytes per batch

__device__ __forceinline__ void gload_lds16b(const uint8_t* g, uint8_t* l) {
  __builtin_amdgcn_global_load_lds((__attribute__((address_space(1))) void*)(g),
                                   (__attribute__((address_space(3))) void*)(l),
                                   16, 0, 0);
}

__device__ __forceinline__ float silu_f(float v) { return v / (1.0f + __expf(-v)); }

__device__ __forceinline__ uint32_t f8x4(float a, float b, float c, float d) {
  int v = __builtin_amdgcn_cvt_pk_fp8_f32(a, b, 0, false);
  v = __builtin_amdgcn_cvt_pk_fp8_f32(c, d, v, true);
  return (uint32_t)v;
}
__device__ __forceinline__ uint8_t f8x1(float a) {
  return (uint8_t)(__builtin_amdgcn_cvt_pk_fp8_f32(a, 0.f, 0, false) & 0xff);
}

// k-permutation within a 128-byte k-tile: [a|s|t|b] -> [a|t|s|b].
// Makes the fragment granule pair (8a+t, 8a+4+t) 16B-contiguous so the core
// reads ds_read_b128. A.B is invariant: SAME perm applied to A and B k-dims.
__device__ __forceinline__ int permk(int kb) {
  int b = kb & 7, t = (kb >> 3) & 3, s = (kb >> 5) & 1, a = (kb >> 6) & 1;
  return (a << 6) | (t << 4) | (s << 3) | b;
}

#define BARRIER() __builtin_amdgcn_s_barrier()

// ---------------------------------------------------------------------------
// Weight transpose: W[K][N] f32 -> WT[N][K] bf16 (for Wqk)
// ---------------------------------------------------------------------------
__global__ __launch_bounds__(256) void k_transpose_bf16(const float* __restrict__ W,
                                                        bf16_t* __restrict__ WT,
                                                        int K, int N) {
  __shared__ float t[32][33];
  int n0 = blockIdx.x * 32, k0 = blockIdx.y * 32;
  int tx = threadIdx.x & 31, ty = threadIdx.x >> 5;
#pragma unroll
  for (int r = 0; r < 32; r += 8)
    t[ty + r][tx] = W[(size_t)(k0 + ty + r) * N + n0 + tx];
  __syncthreads();
#pragma unroll
  for (int r = 0; r < 32; r += 8)
    WT[(size_t)(n0 + ty + r) * K + k0 + tx] = (bf16_t)t[tx][ty + r];
}

// Weight transpose: W[K][N] f32 -> WT[N][K] fp8 (k-permuted), scaled x16
__global__ __launch_bounds__(256) void k_transpose_f8(const float* __restrict__ W,
                                                      uint8_t* __restrict__ WT,
                                                      int K, int N) {
  __shared__ float t[32][33];
  int n0 = blockIdx.x * 32, k0 = blockIdx.y * 32;
  int tx = threadIdx.x & 31, ty = threadIdx.x >> 5;
#pragma unroll
  for (int r = 0; r < 32; r += 8)
    t[ty + r][tx] = W[(size_t)(k0 + ty + r) * N + n0 + tx];
  __syncthreads();
#pragma unroll
  for (int r = 0; r < 32; r += 8) {
    int kt = k0 + tx;
    WT[(size_t)(n0 + ty + r) * K + (kt & ~127) + permk(kt & 127)] =
        f8x1(t[tx][ty + r] * 16.0f);
  }
}

// ---------------------------------------------------------------------------
// LayerNorm: x f32 -> normed bf16 (qk GEMM) + normed fp8 k-permuted (hidden)
// ---------------------------------------------------------------------------
__global__ __launch_bounds__(256) void k_layernorm(const float* __restrict__ x,
                                                   const float* __restrict__ g,
                                                   const float* __restrict__ b,
                                                   bf16_t* __restrict__ out,
                                                   uint8_t* __restrict__ out8) {
  int row = blockIdx.x, t = threadIdx.x;
  const float4* xr = (const float4*)(x + (size_t)row * DIMK);
  float4 v = xr[t];
  float s  = v.x + v.y + v.z + v.w;
  float ss = v.x * v.x + v.y * v.y + v.z * v.z + v.w * v.w;
#pragma unroll
  for (int o = 1; o < 64; o <<= 1) { s += __shfl_xor(s, o); ss += __shfl_xor(ss, o); }
  __shared__ float red[8];
  int wave = t >> 6, lane = t & 63;
  if (lane == 0) { red[wave] = s; red[wave + 4] = ss; }
  __syncthreads();
  s  = red[0] + red[1] + red[2] + red[3];
  ss = red[4] + red[5] + red[6] + red[7];
  float mean = s * (1.0f / DIMK);
  float var  = ss * (1.0f / DIMK) - mean * mean;
  float rstd = rsqrtf(var + 1e-5f);
  float4 gg = ((const float4*)g)[t];
  float4 bb = ((const float4*)b)[t];
  float o0 = (v.x - mean) * rstd * gg.x + bb.x;
  float o1 = (v.y - mean) * rstd * gg.y + bb.y;
  float o2 = (v.z - mean) * rstd * gg.z + bb.z;
  float o3 = (v.w - mean) * rstd * gg.w + bb.w;
  bf16x4 o4; o4[0] = (bf16_t)o0; o4[1] = (bf16_t)o1; o4[2] = (bf16_t)o2; o4[3] = (bf16_t)o3;
  *(bf16x4*)(out + (size_t)row * DIMK + t * 4) = o4;
  int kt = t * 4;
  *(uint32_t*)(out8 + (size_t)row * DIMK + (kt & ~127) + permk(kt & 127)) =
      f8x4(o0, o1, o2, o3);
}

// ---------------------------------------------------------------------------
// fp8 8-phase 256x256 GEMM core, BK=128 (r14 reference: 390.5 us, 0 bank
// conflicts). 512 thr / 8 waves (2M x 4N). All fp8 operands K-PERMUTED
// (permk) so each (kp,t) fragment pair is one 16B LDS chunk; chunk swizzle
// c ^= (row&7) on reads; staging pre-swizzles the global source chunk and
// the LDS dest stays linear. 24 conflict-free ds_read_b128/wave/K-tile.
// Schedule: reads lead their MFMA by one phase; staging A(g+1)@p0/p1,
// B(g+2)@p3; single counted vmcnt(4) per K-tile; raw barriers; setprio.
// ---------------------------------------------------------------------------
#define MFMAQ8(MH, KP)                                                        \
  _Pragma("unroll")                                                           \
  for (int mi = 0; mi < 4; ++mi)                                              \
    _Pragma("unroll")                                                         \
    for (int nj = 0; nj < 4; ++nj)                                            \
      _Pragma("unroll")                                                       \
      for (int ks = 0; ks < 2; ++ks)                                          \
        acc[(MH) * 4 + mi][nj] = MFMAF8(aF[(MH) * 4 + mi][KP][ks],            \
                                        bF[nj][KP][ks], acc[(MH) * 4 + mi][nj]);

#define RDA8(MILO, KP, BUFO)                                                  \
  _Pragma("unroll")                                                           \
  for (int mi = (MILO); mi < (MILO) + 4; ++mi)                                \
    aF[mi][KP] = *(const i64x2*)(pA + (BUFO) + mi * 2048 + swc[KP]);

#define RDB8(KP, BUFO)                                                        \
  _Pragma("unroll")                                                           \
  for (int nj = 0; nj < 4; ++nj)                                              \
    bF[nj][KP] = *(const i64x2*)(pB + (BUFO) + nj * 2048 + swc[KP]);

__device__ __forceinline__ void core8p_f8(const uint8_t* __restrict__ Ag, int lda,
                                          const uint8_t* __restrict__ Bg, int ldb,
                                          int NK, uint8_t* AS, uint8_t* BS,
                                          f32x4 (&acc)[8][4]) {
  const int tid = threadIdx.x, wid = tid >> 6, lane = tid & 63;
  const int wm = wid >> 2, wn = wid & 3;
  const int srow = lane >> 3;                       // row within 8-row chunk
  const int scol = ((lane & 7) ^ srow) * 16;        // pre-swizzled source chunk

  auto stA = [&](int kt, int h) {
    int r0 = h * 128 + wid * 16 + srow;
    uint8_t* d = AS + ((kt & 1) * 2 + h) * 16384 + wid * 2048;
    gload_lds16b(Ag + (size_t)r0 * lda + kt * 128 + scol, d);
    gload_lds16b(Ag + (size_t)(r0 + 8) * lda + kt * 128 + scol, d + 1024);
  };
  auto stB = [&](int kt, int h) {
    int r0 = h * 128 + wid * 16 + srow;
    uint8_t* d = BS + ((kt & 1) * 2 + h) * 16384 + wid * 2048;
    gload_lds16b(Bg + (size_t)r0 * ldb + kt * 128 + scol, d);
    gload_lds16b(Bg + (size_t)(r0 + 8) * ldb + kt * 128 + scol, d + 1024);
  };

  const int t = lane >> 4;
  int swc[2];
  swc[0] = ((0 * 4 + t) ^ (lane & 7)) * 16;
  swc[1] = ((1 * 4 + t) ^ (lane & 7)) * 16;

  const uint8_t* pA = AS + wm * 16384 + (lane & 15) * 128;
  const uint8_t* pB = BS + (wn >> 1) * 16384 + ((wn & 1) * 64 + (lane & 15)) * 128;

  i64x2 aF[8][2], bF[4][2];

  // Prologue: stage A(0),B(0),B(1); drain tile 0 (keep B(1)); read Q0(0).
  stA(0, 0); stA(0, 1); stB(0, 0); stB(0, 1);
  stB(1, 0); stB(1, 1);
  asm volatile("s_waitcnt vmcnt(4)" ::: "memory");
  BARRIER();
  RDA8(0, 0, 0);
  RDB8(0, 0);

  for (int g = 0; g < NK; ++g) {
    const int buf  = (g & 1) * 32768;
    const int nbuf = ((g + 1) & 1) * 32768;
    // p0: read Q1 frags (aF[4..7] kp0); stage A(g+1)h0; MFMA Q0
    RDA8(4, 0, buf);
    if (g + 1 < NK) stA(g + 1, 0);
    BARRIER();
    __builtin_amdgcn_s_setprio(1);
    MFMAQ8(0, 0);
    __builtin_amdgcn_s_setprio(0);
    // p1: read Q2 frags (aF[0..3] kp1 + bF kp1); stage A(g+1)h1; MFMA Q1
    RDA8(0, 1, buf);
    RDB8(1, buf);
    if (g + 1 < NK) stA(g + 1, 1);
    BARRIER();
    __builtin_amdgcn_s_setprio(1);
    MFMAQ8(1, 0);
    __builtin_amdgcn_s_setprio(0);
    // p2: read Q3 frags (aF[4..7] kp1); MFMA Q2
    RDA8(4, 1, buf);
    BARRIER();
    __builtin_amdgcn_s_setprio(1);
    MFMAQ8(0, 1);
    __builtin_amdgcn_s_setprio(0);
    // p3: stage B(g+2); drain tile g+1 (keep B(g+2)); read Q0(g+1); MFMA Q3
    if (g + 2 < NK) {
      stB(g + 2, 0); stB(g + 2, 1);
      asm volatile("s_waitcnt vmcnt(4)" ::: "memory");
    } else if (g + 1 < NK) {
      asm volatile("s_waitcnt vmcnt(0)" ::: "memory");
    }
    BARRIER();
    if (g + 1 < NK) {
      RDA8(0, 0, nbuf);
      RDB8(0, nbuf);
    }
    __builtin_amdgcn_s_setprio(1);
    MFMAQ8(1, 1);
    __builtin_amdgcn_s_setprio(0);
  }
}

// GEMM1: silu(normed @ Wh + bh) -> vT8 (fp8 x16, transposed, tok-permuted) /
// gate bf16.  A = normed8 (s=1), B = Wh8T (s=16): pre-act = acc/16 + bias.
__global__ __launch_bounds__(512, 2) void k_gemm_hidden8p(const uint8_t* __restrict__ A,
                                                          const uint8_t* __restrict__ BT,
                                                          const float* __restrict__ bias,
                                                          uint8_t* __restrict__ vT8,
                                                          bf16_t* __restrict__ gate) {
  extern __shared__ __align__(16) uint8_t lds[];
  uint8_t* AS = lds;
  uint8_t* BS = lds + 65536;
  const int nwg = gridDim.x, bid = blockIdx.x;
  const int swz = (bid & 7) * (nwg >> 3) + (bid >> 3);
  const int mblk = swz >> 4, nblk = swz & 15;            // H2/256 = 16
  const int m0 = mblk * 256, n0 = nblk * 256;
  f32x4 acc[8][4];
#pragma unroll
  for (int i = 0; i < 8; ++i)
#pragma unroll
    for (int j = 0; j < 4; ++j) acc[i][j] = (f32x4){0.f, 0.f, 0.f, 0.f};
  core8p_f8(A + (size_t)m0 * DIMK, DIMK, BT + (size_t)n0 * DIMK, DIMK,
            DIMK / 128, AS, BS, acc);

  const int tid = threadIdx.x, wid = tid >> 6, lane = tid & 63;
  const int wm = wid >> 2, wn = wid & 3;
  const int row0 = m0 + wm * 128, col0 = n0 + wn * 64;
#pragma unroll
  for (int mi = 0; mi < 8; ++mi)
#pragma unroll
    for (int nj = 0; nj < 4; ++nj) {
      int col = col0 + nj * 16 + (lane & 15);
      float bv = bias[col];
      int row = row0 + mi * 16 + ((lane >> 4) << 2);
      float sv[4];
#pragma unroll
      for (int r = 0; r < 4; ++r) sv[r] = silu_f(acc[mi][nj][r] * 0.0625f + bv);
      if (col < HID) {
        *(uint32_t*)(vT8 + (size_t)col * TOKS + (row & ~127) + permk(row & 127)) =
            f8x4(sv[0] * 16.f, sv[1] * 16.f, sv[2] * 16.f, sv[3] * 16.f);
      } else {
#pragma unroll
        for (int r = 0; r < 4; ++r)
          gate[(size_t)(row + r) * HID + (col - HID)] = (bf16_t)sv[r];
      }
    }
}

// Final GEMM: out = gated @ Wo + bo + x. A = gated8 (x256), B = Wo8T (x16).
__global__ __launch_bounds__(512, 2) void k_gemm_out8p(const uint8_t* __restrict__ A,
                                                       const uint8_t* __restrict__ BT,
                                                       const float* __restrict__ bo,
                                                       const float* __restrict__ x,
                                                       float* __restrict__ out) {
  extern __shared__ __align__(16) uint8_t lds[];
  uint8_t* AS = lds;
  uint8_t* BS = lds + 65536;
  const int nwg = gridDim.x, bid = blockIdx.x;
  const int swz = (bid & 7) * (nwg >> 3) + (bid >> 3);
  const int mblk = swz >> 2, nblk = swz & 3;             // DIMK/256 = 4
  const int m0 = mblk * 256, n0 = nblk * 256;
  f32x4 acc[8][4];
#pragma unroll
  for (int i = 0; i < 8; ++i)
#pragma unroll
    for (int j = 0; j < 4; ++j) acc[i][j] = (f32x4){0.f, 0.f, 0.f, 0.f};
  core8p_f8(A + (size_t)m0 * HID, HID, BT + (size_t)n0 * HID, HID,
            HID / 128, AS, BS, acc);

  const int tid = threadIdx.x, wid = tid >> 6, lane = tid & 63;
  const int wm = wid >> 2, wn = wid & 3;
  const int row0 = m0 + wm * 128, col0 = n0 + wn * 64;
#pragma unroll
  for (int mi = 0; mi < 8; ++mi)
#pragma unroll
    for (int nj = 0; nj < 4; ++nj) {
      int col = col0 + nj * 16 + (lane & 15);
      float bv = bo[col];
      int row = row0 + mi * 16 + ((lane >> 4) << 2);
#pragma unroll
      for (int r = 0; r < 4; ++r) {
        size_t gi = (size_t)(row + r) * DIMK + col;
        out[gi] = acc[mi][nj][r] * (1.0f / 4096.0f) + bv + x[gi];
      }
    }
}

// PV: A = P8 (x2^18, j-permuted panels), B = vT8 (x16, tok-permuted);
// heavy-first grid. gated8 = fp8(acc * gate * 2^-14), k(HID)-permuted.
__global__ __launch_bounds__(512, 2) void k_pv8p(const uint8_t* __restrict__ P8,
                                                 const uint8_t* __restrict__ vT8,
                                                 const bf16_t* __restrict__ gate,
                                                 uint8_t* __restrict__ gated8) {
  extern __shared__ __align__(16) uint8_t lds[];
  uint8_t* AS = lds;
  uint8_t* BS = lds + 65536;
  const int w = blockIdx.x;
  const int rb = 15 - (w >> 5);
  const int hb = (w >> 2) & 7;
  const int bb = w & 3;
  const int lda = (rb + 1) * 256;
  const uint8_t* Ag = P8 + (size_t)bb * PBATCH + (size_t)65536 * (rb * (rb + 1) / 2);
  const uint8_t* Bg = vT8 + (size_t)(hb * 256) * TOKS + (size_t)bb * SEQ;
  f32x4 acc[8][4];
#pragma unroll
  for (int i = 0; i < 8; ++i)
#pragma unroll
    for (int j = 0; j < 4; ++j) acc[i][j] = (f32x4){0.f, 0.f, 0.f, 0.f};
  core8p_f8(Ag, lda, Bg, TOKS, (rb + 1) * 2, AS, BS, acc);

  const int tid = threadIdx.x, wid = tid >> 6, lane = tid & 63;
  const int wm = wid >> 2, wn = wid & 3;
  const int row0 = rb * 256 + wm * 128, col0 = hb * 256 + wn * 64;
#pragma unroll
  for (int mi = 0; mi < 8; ++mi)
#pragma unroll
    for (int nj = 0; nj < 4; ++nj) {
      int col = col0 + nj * 16 + (lane & 15);
      int pcol = (col & ~127) | permk(col & 127);
#pragma unroll
      for (int r = 0; r < 4; ++r) {
        int row = row0 + mi * 16 + ((lane >> 4) << 2) + r;
        size_t tok = (size_t)(bb * SEQ + row);
        float gv = (float)gate[tok * HID + col];
        gated8[tok * HID + pcol] = f8x1(acc[mi][nj][r] * gv * 6.103515625e-05f);
      }
    }
}

// ---------------------------------------------------------------------------
// 128x128 m97-style bf16 core (kept for qk / qkt)
// ---------------------------------------------------------------------------
__device__ __forceinline__ void gload_lds16(const bf16_t* g, bf16_t* l) {
  __builtin_amdgcn_global_load_lds((__attribute__((address_space(1))) void*)(g),
                                   (__attribute__((address_space(3))) void*)(l),
                                   16, 0, 0);
}

__device__ __forceinline__ void gemm_core_std(const bf16_t* __restrict__ Ag0, int lda,
                                              const bf16_t* __restrict__ Bg0, int ldb,
                                              int K, bf16_t* As, bf16_t* Bs,
                                              f32x4 acc[4][4]) {
  const int tid = threadIdx.x;
  const int wave = tid >> 6, lane = tid & 63;
  bf16_t* asw = As + wave * 32 * 32;
  bf16_t* bsw = Bs + wave * 32 * 32;
  const int ar = ((wave >> 1) * 64 + (lane & 15)) * 32 + (lane >> 4) * 8;
  const int br = ((wave & 1) * 64 + (lane & 15)) * 32 + (lane >> 4) * 8;
  for (int k0 = 0; k0 < K; k0 += 32) {
    __syncthreads();
    gload_lds16(Ag0 + k0, asw);
    gload_lds16(Ag0 + k0 + 16 * lda, asw + 16 * 32);
    gload_lds16(Bg0 + k0, bsw);
    gload_lds16(Bg0 + k0 + 16 * ldb, bsw + 16 * 32);
    __syncthreads();
    bf16x8 af[4], bfr[4];
#pragma unroll
    for (int m = 0; m < 4; m++) af[m] = *(const bf16x8*)(As + ar + m * 16 * 32);
#pragma unroll
    for (int n = 0; n < 4; n++) bfr[n] = *(const bf16x8*)(Bs + br + n * 16 * 32);
#pragma unroll
    for (int m = 0; m < 4; m++)
#pragma unroll
      for (int n = 0; n < 4; n++) acc[m][n] = MFMA16(af[m], bfr[n], acc[m][n]);
  }
}

// qk GEMM (bf16): qkv = silu(normed @ Wqk + bqk); q/k = qkv*gamma+beta
__global__ __launch_bounds__(256) void k_gemm_qk(const bf16_t* __restrict__ A,
                                                 const bf16_t* __restrict__ BT,
                                                 const float* __restrict__ bias,
                                                 const float* __restrict__ osg,
                                                 const float* __restrict__ osb,
                                                 bf16_t* __restrict__ qo,
                                                 bf16_t* __restrict__ ko) {
  __shared__ __align__(16) bf16_t As[128 * 32];
  __shared__ __align__(16) bf16_t Bs[128 * 32];
  const int tid = threadIdx.x, wave = tid >> 6, lane = tid & 63;
  const int m0 = blockIdx.y * 128;
  const bf16_t* Ag0 = A + (size_t)(m0 + wave * 32 + (lane >> 2)) * DIMK + (lane & 3) * 8;
  const bf16_t* Bg0 = BT + (size_t)(wave * 32 + (lane >> 2)) * DIMK + (lane & 3) * 8;
  f32x4 acc[4][4];
#pragma unroll
  for (int m = 0; m < 4; m++)
#pragma unroll
    for (int n = 0; n < 4; n++) acc[m][n] = (f32x4){0.f, 0.f, 0.f, 0.f};
  gemm_core_std(Ag0, DIMK, Bg0, DIMK, DIMK, As, Bs, acc);

  const int row0 = m0 + (wave >> 1) * 64;
  const int col0 = (wave & 1) * 64;
#pragma unroll
  for (int m = 0; m < 4; m++) {
#pragma unroll
    for (int n = 0; n < 4; n++) {
      int col = col0 + n * 16 + (lane & 15);
      float bv = bias[col];
      float g0 = osg[col], b0 = osb[col];
      float g1 = osg[QKD + col], b1 = osb[QKD + col];
      int row = row0 + m * 16 + ((lane >> 4) << 2);
#pragma unroll
      for (int r = 0; r < 4; r++) {
        float sv = silu_f(acc[m][n][r] + bv);
        qo[(size_t)(row + r) * QKD + col] = (bf16_t)(sv * g0 + b0);
        ko[(size_t)(row + r) * QKD + col] = (bf16_t)(sv * g1 + b1);
      }
    }
  }
}

// Pass A (bf16 core): P = relu((q@k^T)/(i+1))^2, causal, written fp8 x2^18
// j-PERMUTED into rect per-(bb,rb) panels. Even-ib jb=ib+1 tile = zeros
// (permutation-invariant: whole tile zeroed).
__global__ __launch_bounds__(256) void k_qkt(const bf16_t* __restrict__ qb,
                                             const bf16_t* __restrict__ kb,
                                             uint8_t* __restrict__ P8) {
  const int jb = blockIdx.x, ib = blockIdx.y, bb = blockIdx.z;
  const int rb = ib >> 1;
  if (jb > 2 * rb + 1) return;
  const int lda = (rb + 1) * 256;
  uint8_t* Pt = P8 + (size_t)bb * PBATCH + (size_t)65536 * (rb * (rb + 1) / 2)
              + (size_t)((ib & 1) * 128) * lda + jb * 128;
  if (jb == ib + 1) {  // fully masked tile -> zeros
    const int row = threadIdx.x >> 1, cb = (threadIdx.x & 1) * 64;
    uint4 z = {0, 0, 0, 0};
#pragma unroll
    for (int c = 0; c < 64; c += 16)
      *(uint4*)(Pt + (size_t)row * lda + cb + c) = z;
    return;
  }
  __shared__ __align__(16) bf16_t As[128 * 32];
  __shared__ __align__(16) bf16_t Bs[128 * 32];
  const int tid = threadIdx.x, wave = tid >> 6, lane = tid & 63;
  const bf16_t* Ag0 = qb + (size_t)(bb * SEQ + ib * 128 + wave * 32 + (lane >> 2)) * QKD + (lane & 3) * 8;
  const bf16_t* Bg0 = kb + (size_t)(bb * SEQ + jb * 128 + wave * 32 + (lane >> 2)) * QKD + (lane & 3) * 8;
  f32x4 acc[4][4];
#pragma unroll
  for (int m = 0; m < 4; m++)
#pragma unroll
    for (int n = 0; n < 4; n++) acc[m][n] = (f32x4){0.f, 0.f, 0.f, 0.f};
  gemm_core_std(Ag0, QKD, Bg0, QKD, QKD, As, Bs, acc);

  const int il0 = (wave >> 1) * 64, jl0 = (wave & 1) * 64;
#pragma unroll
  for (int m = 0; m < 4; m++) {
#pragma unroll
    for (int n = 0; n < 4; n++) {
      int jloc = jl0 + n * 16 + (lane & 15);
      int jg = jb * 128 + jloc;
      int jp = permk(jloc);
#pragma unroll
      for (int r = 0; r < 4; r++) {
        int iloc = il0 + m * 16 + ((lane >> 4) << 2) + r;
        int ig = ib * 128 + iloc;
        float sv = acc[m][n][r] / (float)(ig + 1);
        sv = fmaxf(sv, 0.f);
        sv *= sv;
        if (jg > ig) sv = 0.f;
        Pt[(size_t)iloc * lda + jp] = f8x1(sv * 262144.0f);  // x2^18
      }
    }
  }
}

// ---------------------------------------------------------------------------
extern "C" void kernel_launch(void* const* d_in, const int* in_sizes, int n_in,
                              void* d_out, int out_size, void* d_ws, size_t ws_size,
                              hipStream_t stream) {
  (void)in_sizes; (void)n_in; (void)out_size; (void)ws_size;
  const float* x    = (const float*)d_in[0];
  const float* ln_g = (const float*)d_in[1];
  const float* ln_b = (const float*)d_in[2];
  const float* Wh   = (const float*)d_in[3];
  const float* bh   = (const float*)d_in[4];
  const float* Wqk  = (const float*)d_in[5];
  const float* bqk  = (const float*)d_in[6];
  const float* osg  = (const float*)d_in[7];
  const float* osb  = (const float*)d_in[8];
  const float* Wo   = (const float*)d_in[9];
  const float* bo   = (const float*)d_in[10];
  float* out = (float*)d_out;

  char* ws = (char*)d_ws;
  bf16_t* normed  = (bf16_t*)ws;  ws += (size_t)TOKS * DIMK * 2;   // 32 MB
  uint8_t* normed8 = (uint8_t*)ws; ws += (size_t)TOKS * DIMK;      // 16 MB
  bf16_t* WqkT    = (bf16_t*)ws;  ws += (size_t)QKD * DIMK * 2;    // 0.25 MB
  uint8_t* Wh8T   = (uint8_t*)ws; ws += (size_t)H2 * DIMK;         // 4 MB
  uint8_t* Wo8T   = (uint8_t*)ws; ws += (size_t)DIMK * HID;        // 2 MB
  bf16_t* gate    = (bf16_t*)ws;  ws += (size_t)TOKS * HID * 2;    // 64 MB
  uint8_t* vT8    = (uint8_t*)ws; ws += (size_t)HID * TOKS;        // 32 MB
  uint8_t* gated8 = (uint8_t*)ws; ws += (size_t)TOKS * HID;        // 32 MB
  bf16_t* qb      = (bf16_t*)ws;  ws += (size_t)TOKS * QKD * 2;    // 4 MB
  bf16_t* kb      = (bf16_t*)ws;  ws += (size_t)TOKS * QKD * 2;    // 4 MB
  uint8_t* P8     = (uint8_t*)ws; ws += (size_t)4 * PBATCH;        // 35.7 MB

  hipFuncSetAttribute((const void*)k_gemm_hidden8p,
                      hipFuncAttributeMaxDynamicSharedMemorySize, SMEM8P);
  hipFuncSetAttribute((const void*)k_gemm_out8p,
                      hipFuncAttributeMaxDynamicSharedMemorySize, SMEM8P);
  hipFuncSetAttribute((const void*)k_pv8p,
                      hipFuncAttributeMaxDynamicSharedMemorySize, SMEM8P);

  k_transpose_f8<<<dim3(H2 / 32, DIMK / 32), 256, 0, stream>>>(Wh, Wh8T, DIMK, H2);
  k_transpose_f8<<<dim3(DIMK / 32, HID / 32), 256, 0, stream>>>(Wo, Wo8T, HID, DIMK);
  k_transpose_bf16<<<dim3(QKD / 32, DIMK / 32), 256, 0, stream>>>(Wqk, WqkT, DIMK, QKD);
  k_layernorm<<<TOKS, 256, 0, stream>>>(x, ln_g, ln_b, normed, normed8);
  k_gemm_hidden8p<<<dim3((TOKS / 256) * (H2 / 256)), 512, SMEM8P, stream>>>(normed8, Wh8T, bh, vT8, gate);
  k_gemm_qk<<<dim3(1, TOKS / 128), 256, 0, stream>>>(normed, WqkT, bqk, osg, osb, qb, kb);
  k_qkt<<<dim3(SEQ / 128, SEQ / 128, 4), 256, 0, stream>>>(qb, kb, P8);
  k_pv8p<<<dim3(16 * 8 * 4), 512, SMEM8P, stream>>>(P8, vT8, gate, gated8);
  k_gemm_out8p<<<dim3((TOKS / 256) * (DIMK / 256)), 512, SMEM8P, stream>>>(gated8, Wo8T, bo, x, out);
}